// Round 3
// baseline (337.365 us; speedup 1.0000x reference)
//
#include <hip/hip_runtime.h>
#include <math.h>
#include <stdint.h>

// LabelSmoothingTarget: loss = mean_i( 0.9 * (lse_i - x[i, t_i]) + 0.01 * |1 - (x[i, 9] - lse_i)| )
// lse_i = logsumexp over row i of x [B=4096, C=50257] fp32.
// Memory-bound: ~824 MB read once; fp32-read ceiling ~6.29 TB/s -> ~131 us floor.
// R2 hit 139.1 us (row kernel ~6.2 TB/s, at ceiling). R3: fuse the mean via
// deterministic fixed-point atomics + last-block pattern to kill the second
// launch + gap (~5-7 us of serial overhead).

#define BB 4096
#define CC 50257
#define TGT_CLASS 9
#define NTHREADS 256
#define FIXED_SCALE 1048576.0f  // 2^20; per-row quantization error 2^-21 << 0.206 threshold

typedef float floatx4 __attribute__((ext_vector_type(4)));

__device__ __forceinline__ void lse_combine(float& m, float& s, float m2, float s2) {
    float M = fmaxf(m, m2);
    s = s * __expf(m - M) + s2 * __expf(m2 - M);
    m = M;
}

__device__ __forceinline__ void proc4(const floatx4 v, float& m, float& s) {
    float cm = fmaxf(fmaxf(v.x, v.y), fmaxf(v.z, v.w));
    if (cm > m) {               // rare after warm-up
        s *= __expf(m - cm);
        m = cm;
    }
    float e0 = __expf(v.x - m);
    float e1 = __expf(v.y - m);
    float e2 = __expf(v.z - m);
    float e3 = __expf(v.w - m);
    s += (e0 + e1) + (e2 + e3);  // explicit tree: 2-deep instead of 4-deep chain
}

__global__ __launch_bounds__(NTHREADS) void row_loss_kernel(const float* __restrict__ x,
                                                            const int* __restrict__ target,
                                                            unsigned long long* __restrict__ acc,
                                                            unsigned int* __restrict__ cnt,
                                                            float* __restrict__ out) {
    const int r = blockIdx.x;
    const float* __restrict__ row = x + (size_t)r * CC;
    const int tid = threadIdx.x;

    // Two independent online-logsumexp states for ILP
    float m0 = -INFINITY, s0 = 0.0f;
    float m1 = -INFINITY, s1 = 0.0f;

    // Alignment peel: row base is only 4B-aligned (C odd).
    const int pre = (int)(((16u - ((uint32_t)(uintptr_t)row & 15u)) & 15u) >> 2);
    if (tid < pre) {
        m0 = row[tid];
        s0 = 1.0f;
    }

    const floatx4* __restrict__ vp = (const floatx4*)(row + pre);
    const int nvec = (CC - pre) >> 2;
    const int rem  = (CC - pre) & 3;

    int i = tid;
    for (; i + NTHREADS < nvec; i += 2 * NTHREADS) {
        floatx4 a = __builtin_nontemporal_load(vp + i);
        floatx4 b = __builtin_nontemporal_load(vp + i + NTHREADS);
        proc4(a, m0, s0);
        proc4(b, m1, s1);
    }
    if (i < nvec) {
        floatx4 a = __builtin_nontemporal_load(vp + i);
        proc4(a, m0, s0);
    }
    if (tid < rem) {
        float v = row[pre + (nvec << 2) + tid];
        if (v > m0) { s0 *= __expf(m0 - v); m0 = v; }
        s0 += __expf(v - m0);
    }

    // Merge dual states (every lane has finite m0: >=24 chunks each; exp(-inf)=0 safe)
    lse_combine(m0, s0, m1, s1);

    // Wave (64-lane) butterfly reduce
    #pragma unroll
    for (int off = 1; off < 64; off <<= 1) {
        float m2 = __shfl_xor(m0, off);
        float s2 = __shfl_xor(s0, off);
        lse_combine(m0, s0, m2, s2);
    }

    // Cross-wave reduce via LDS (4 waves)
    __shared__ float sm[NTHREADS / 64];
    __shared__ float ss[NTHREADS / 64];
    const int wid  = tid >> 6;
    const int lane = tid & 63;
    if (lane == 0) { sm[wid] = m0; ss[wid] = s0; }
    __syncthreads();

    if (tid == 0) {
        float M = sm[0], S = ss[0];
        #pragma unroll
        for (int w = 1; w < NTHREADS / 64; ++w) lse_combine(M, S, sm[w], ss[w]);
        const float lse = M + __logf(S);

        const int t = target[r];
        const float xt = row[t];
        const float x9 = row[TGT_CLASS];

        const float nll    = lse - xt;                  // -(x_t - lse)
        const float smooth = fabsf(1.0f - (x9 - lse));  // |1 - logprob_9|
        const float loss   = 0.9f * nll + 0.01f * smooth;  // always > 0 here

        // Deterministic fixed-point accumulation (integer adds commute bitwise)
        atomicAdd(acc, (unsigned long long)llrintf(loss * FIXED_SCALE));
        __threadfence();                                 // make add visible device-wide
        unsigned int done = atomicAdd(cnt, 1u);
        if (done == (unsigned int)(gridDim.x - 1)) {
            // last block: all adds are visible (fence-before-increment on every block)
            unsigned long long total = atomicAdd(acc, 0ULL);  // atomic read
            out[0] = (float)((double)total * (1.0 / ((double)FIXED_SCALE * (double)BB)));
        }
    }
}

extern "C" void kernel_launch(void* const* d_in, const int* in_sizes, int n_in,
                              void* d_out, int out_size, void* d_ws, size_t ws_size,
                              hipStream_t stream) {
    const float* x      = (const float*)d_in[0];
    const int*   target = (const int*)d_in[1];
    float* out = (float*)d_out;

    unsigned long long* acc = (unsigned long long*)d_ws;      // 8 B
    unsigned int*       cnt = (unsigned int*)((char*)d_ws + 8); // 4 B

    // Zero accumulator + counter each call (graph-captures as a memset node)
    hipMemsetAsync(d_ws, 0, 16, stream);

    row_loss_kernel<<<BB, NTHREADS, 0, stream>>>(x, target, acc, cnt, out);
}

// Round 4
// 135.583 us; speedup vs baseline: 2.4883x; 2.4883x over previous
//
#include <hip/hip_runtime.h>
#include <math.h>
#include <stdint.h>

// LabelSmoothingTarget: loss = mean_i( 0.9 * (lse_i - x[i, t_i]) + 0.01 * |1 - (x[i, 9] - lse_i)| )
// lse_i = logsumexp over row i of x [B=4096, C=50257] fp32.
// Memory-bound: ~824 MB read once; fp32-read ceiling ~6.29 TB/s -> ~131 us floor.
// R2 (this structure) hit 139.1 us; row kernel ~6.2 TB/s ~= 98% of read ceiling.
// R3's atomic fusion regressed 2.4x (cross-XCD contended atomics + device fences
// serialize ~200us on MI355X) -> reverted. R4 = R2 + micro-tweaks:
// target[r] prefetched before the stream (overlaps gather latency), 1024-thread
// mean kernel (shorter tail).

#define BB 4096
#define CC 50257
#define TGT_CLASS 9
#define NTHREADS 256
#define MTHREADS 1024

typedef float floatx4 __attribute__((ext_vector_type(4)));

__device__ __forceinline__ void lse_combine(float& m, float& s, float m2, float s2) {
    float M = fmaxf(m, m2);
    s = s * __expf(m - M) + s2 * __expf(m2 - M);
    m = M;
}

__device__ __forceinline__ void proc4(const floatx4 v, float& m, float& s) {
    float cm = fmaxf(fmaxf(v.x, v.y), fmaxf(v.z, v.w));
    if (cm > m) {               // rare after warm-up
        s *= __expf(m - cm);
        m = cm;
    }
    float e0 = __expf(v.x - m);
    float e1 = __expf(v.y - m);
    float e2 = __expf(v.z - m);
    float e3 = __expf(v.w - m);
    s += (e0 + e1) + (e2 + e3);  // explicit tree: 2-deep instead of 4-deep chain
}

__global__ __launch_bounds__(NTHREADS) void row_loss_kernel(const float* __restrict__ x,
                                                            const int* __restrict__ target,
                                                            float* __restrict__ row_loss) {
    const int r = blockIdx.x;
    const float* __restrict__ row = x + (size_t)r * CC;
    const int tid = threadIdx.x;

    // Prefetch the target index (and kick off nothing else dependent on it);
    // the gather row[t] happens in the epilogue but t is ready by then.
    int t = 0;
    if (tid == 0) t = target[r];

    // Two independent online-logsumexp states for ILP
    float m0 = -INFINITY, s0 = 0.0f;
    float m1 = -INFINITY, s1 = 0.0f;

    // Alignment peel: row base is only 4B-aligned (C odd).
    const int pre = (int)(((16u - ((uint32_t)(uintptr_t)row & 15u)) & 15u) >> 2);
    if (tid < pre) {
        m0 = row[tid];
        s0 = 1.0f;
    }

    const floatx4* __restrict__ vp = (const floatx4*)(row + pre);
    const int nvec = (CC - pre) >> 2;
    const int rem  = (CC - pre) & 3;

    int i = tid;
    for (; i + NTHREADS < nvec; i += 2 * NTHREADS) {
        floatx4 a = __builtin_nontemporal_load(vp + i);
        floatx4 b = __builtin_nontemporal_load(vp + i + NTHREADS);
        proc4(a, m0, s0);
        proc4(b, m1, s1);
    }
    if (i < nvec) {
        floatx4 a = __builtin_nontemporal_load(vp + i);
        proc4(a, m0, s0);
    }
    if (tid < rem) {
        float v = row[pre + (nvec << 2) + tid];
        if (v > m0) { s0 *= __expf(m0 - v); m0 = v; }
        s0 += __expf(v - m0);
    }

    // Merge dual states (every lane has finite m0: >=24 chunks each; exp(-inf)=0 safe)
    lse_combine(m0, s0, m1, s1);

    // Wave (64-lane) butterfly reduce
    #pragma unroll
    for (int off = 1; off < 64; off <<= 1) {
        float m2 = __shfl_xor(m0, off);
        float s2 = __shfl_xor(s0, off);
        lse_combine(m0, s0, m2, s2);
    }

    // Cross-wave reduce via LDS (4 waves)
    __shared__ float sm[NTHREADS / 64];
    __shared__ float ss[NTHREADS / 64];
    const int wid  = tid >> 6;
    const int lane = tid & 63;
    if (lane == 0) { sm[wid] = m0; ss[wid] = s0; }
    __syncthreads();

    if (tid == 0) {
        float M = sm[0], S = ss[0];
        #pragma unroll
        for (int w = 1; w < NTHREADS / 64; ++w) lse_combine(M, S, sm[w], ss[w]);
        const float lse = M + __logf(S);

        const float xt = row[t];
        const float x9 = row[TGT_CLASS];

        const float nll    = lse - xt;                  // -(x_t - lse)
        const float smooth = fabsf(1.0f - (x9 - lse));  // |1 - logprob_9|
        row_loss[r] = 0.9f * nll + 0.01f * smooth;      // confidence*nll + 0.1*smoothing*smooth
    }
}

__global__ __launch_bounds__(MTHREADS) void mean_kernel(const float* __restrict__ row_loss,
                                                        float* __restrict__ out) {
    float acc = 0.0f;
    #pragma unroll
    for (int i = threadIdx.x; i < BB; i += MTHREADS) acc += row_loss[i];

    #pragma unroll
    for (int off = 1; off < 64; off <<= 1) acc += __shfl_xor(acc, off);

    __shared__ float sacc[MTHREADS / 64];
    const int wid  = threadIdx.x >> 6;
    const int lane = threadIdx.x & 63;
    if (lane == 0) sacc[wid] = acc;
    __syncthreads();

    if (threadIdx.x == 0) {
        float t = 0.0f;
        #pragma unroll
        for (int w = 0; w < MTHREADS / 64; ++w) t += sacc[w];
        out[0] = t * (1.0f / BB);
    }
}

extern "C" void kernel_launch(void* const* d_in, const int* in_sizes, int n_in,
                              void* d_out, int out_size, void* d_ws, size_t ws_size,
                              hipStream_t stream) {
    const float* x      = (const float*)d_in[0];
    const int*   target = (const int*)d_in[1];
    float* out = (float*)d_out;
    float* ws  = (float*)d_ws;  // B floats of per-row loss

    row_loss_kernel<<<BB, NTHREADS, 0, stream>>>(x, target, ws);
    mean_kernel<<<1, MTHREADS, 0, stream>>>(ws, out);
}